// Round 7
// baseline (134.182 us; speedup 1.0000x reference)
//
#include <hip/hip_runtime.h>
#include <stdint.h>

// SetAbstraction forward, MI355X. B=2, N=4096, CIN=64, COUT=128, K=24.
// R7: k_final fragment-resident epilogue — MFMA computes D=F*ww^T so each lane's
// fragment holds all-k for fixed o within a 4-lane (lh) group; softmax via
// masked shfl_xor(16/32) butterfly. No M-in-LDS round trip; G staged bf16;
// LDS 25.8KB -> 6 blocks/CU; 3 barriers. Other kernels unchanged from R6.

#define BB 2
#define NN 4096
#define CI 64
#define CO 128
#define KK 24
#define GQ (BB*NN)        // 8192
#define NKK (NN*KK)       // 98304

typedef __attribute__((ext_vector_type(8))) short short8;
typedef __attribute__((ext_vector_type(4))) float f32x4;

__device__ __forceinline__ float relu_(float x){ return fmaxf(x, 0.0f); }
__device__ __forceinline__ unsigned short f2bf(float x){
    unsigned int u = __float_as_uint(x);
    return (unsigned short)((u + 0x7FFFu + ((u>>16)&1u)) >> 16);
}
__device__ __forceinline__ float bfbits2f(unsigned short u){
    return __uint_as_float(((unsigned int)u) << 16);
}

// ---------- kernel 1: f1T[b][n][o] = relu(bn(w1 @ f)) + prep ----------
__global__ __launch_bounds__(256) void k_f1(const float* __restrict__ f, const float* __restrict__ w1,
                     const float* __restrict__ g1, const float* __restrict__ b1,
                     const float* __restrict__ pc, const float* __restrict__ ww,
                     float* __restrict__ f1T, float* __restrict__ outPc,
                     float* __restrict__ p, float* __restrict__ pS,
                     unsigned short* __restrict__ wwAbf)
{
    int tid = threadIdx.x;
    int bid = blockIdx.x;
    {   // prep (grid 512 covers 49152 and 16384)
        int t = bid*256 + tid;
        if (t < BB*NN*6) {
            float v = pc[t];
            outPc[t] = v;
            int d = t % 6;
            if (d < 3) {
                int q = t/6;
                p[q*3 + d] = v;
                pS[d*GQ + q] = v;       // SoA: pS[d][b*4096+n]
            }
        }
        if (t < CO*CO) {
            int o = t >> 7, c = t & 127;
            int otile = o >> 4, m = o & 15;
            int ks = c >> 5, kk = c & 31;
            int lane = m | ((kk >> 3) << 4);
            int j = kk & 7;
            wwAbf[(((otile*4 + ks)*64 + lane)<<3) + j] = f2bf(ww[t]);
        }
    }
    __shared__ float W[CI*129];
    __shared__ float ft[CI*16];
    for (int i = tid; i < CI*CO; i += 256) {
        int o = i >> 6, c = i & 63;
        W[c*129 + o] = w1[i];
    }
    int b = bid >> 8;
    int n0 = (bid & 255) * 16;
    {
        int c = tid >> 2, nn = (tid & 3) * 4;
        float4 v = *(const float4*)(f + (size_t)b*CI*NN + (size_t)c*NN + n0 + nn);
        *(float4*)&ft[c*16 + nn] = v;
    }
    __syncthreads();
    int o = tid & 127, g = tid >> 7;
    float acc[8];
    #pragma unroll
    for (int j = 0; j < 8; ++j) acc[j] = 0.f;
    const float* ftg = ft + g*8;
    #pragma unroll 8
    for (int c = 0; c < CI; ++c) {
        float w = W[c*129 + o];
        float4 fa = *(const float4*)&ftg[c*16];
        float4 fb4 = *(const float4*)&ftg[c*16 + 4];
        acc[0] += w*fa.x;  acc[1] += w*fa.y;  acc[2] += w*fa.z;  acc[3] += w*fa.w;
        acc[4] += w*fb4.x; acc[5] += w*fb4.y; acc[6] += w*fb4.z; acc[7] += w*fb4.w;
    }
    float sc = g1[o] / sqrtf(1.00001f);
    float bo = b1[o];
    #pragma unroll
    for (int j = 0; j < 8; ++j) {
        int n = n0 + g*8 + j;
        f1T[((size_t)b*NN + n)*CO + o] = relu_(acc[j]*sc + bo);
    }
}

// ---------- kernel 2: ball query 1 -> idx (B,N,K), SoA point loads ----------
__global__ void k_bq1(const float* __restrict__ pS, int* __restrict__ idx)
{
    int wave = threadIdx.x >> 6;
    int lane = threadIdx.x & 63;
    int q = blockIdx.x*4 + wave;          // 0..8191
    int b = q >> 12;
    int n = q & 4095;
    int boff = b << 12;
    const float* Sx = pS + boff;
    const float* Sy = pS + GQ + boff;
    const float* Sz = pS + 2*GQ + boff;
    float qx = Sx[n], qy = Sy[n], qz = Sz[n];
    float sq = qx*qx + qy*qy + qz*qz;
    const float rsq = (float)(0.15*0.15);
    int cnt = 0, first = 0;
    int* orow = idx + (size_t)q*KK;
    for (int chunk = 0; chunk < 64; ++chunk) {
        int s = chunk*64 + lane;
        float sx = Sx[s], sy = Sy[s], sz = Sz[s];
        float ss  = sx*sx + sy*sy + sz*sz;
        float dot = qx*sx + qy*sy + qz*sz;
        float d2 = (sq + ss) - 2.0f*dot;
        unsigned long long m = __ballot(d2 < rsq);
        while (m && cnt < KK) {
            int pos = __ffsll((unsigned long long)m) - 1;
            int sidx = chunk*64 + pos;
            if (cnt == 0) first = sidx;
            if (lane == 0) orow[cnt] = sidx;
            ++cnt;
            m &= m - 1;
        }
        if (cnt >= KK) break;
    }
    if (lane == 0)
        for (int j = cnt; j < KK; ++j) orow[j] = first;
}

// ---------- kernel 3: fused mkdp + FPS (k_geo) ----------
__global__ __launch_bounds__(256) void k_geo(const float* __restrict__ p, const int* __restrict__ idx,
                                             float* __restrict__ dpf, float* __restrict__ ndp)
{
    int tid = threadIdx.x;
    int lane = tid & 31;                 // = k
    int row = blockIdx.x*8 + (tid >> 5); // grid 1024
    float px = 0.f, py = 0.f, pz = 0.f, dist;
    if (lane < KK) {
        float v[3];
        #pragma unroll
        for (int d = 0; d < 3; ++d) {
            int u = 3*lane + d;          // 0..71
            int qq = u / 24;             // 0..2
            int kk = u - qq*24;
            int m = row*3 + qq;          // block index in (B,3,N) blocks of 24
            int b = (m >= 3*NN) ? 1 : 0;
            int rem = m - b*3*NN;
            int dd = rem >> 12;          // /4096
            int n = rem & 4095;
            int base = (b << 12);
            int j = idx[((size_t)(base + n))*KK + kk];
            v[d] = p[(base + j)*3 + dd] - p[(base + n)*3 + dd];
        }
        px = v[0]; py = v[1]; pz = v[2];
        dist = 1e10f;
        float* drow = dpf + (size_t)row*72 + lane*3;
        drow[0] = px; drow[1] = py; drow[2] = pz;
    } else {
        dist = -3.4e38f;                 // idle lanes never win argmax
    }
    float* dst = ndp + (size_t)row*72;
    if (lane == 0) { dst[0] = px; dst[1] = py; dst[2] = pz; }
    int last = 0;
    for (int j = 1; j < KK; ++j) {
        float lx = __shfl(px, last, 32);
        float ly = __shfl(py, last, 32);
        float lz = __shfl(pz, last, 32);
        float dx = px-lx, dy = py-ly, dz = pz-lz;
        float d = dx*dx + dy*dy + dz*dz;
        dist = fminf(dist, d);
        float val = dist; int idxl = lane;
        #pragma unroll
        for (int off = 16; off > 0; off >>= 1) {
            float ov = __shfl_xor(val, off, 32);
            int   oi = __shfl_xor(idxl, off, 32);
            if (ov > val || (ov == val && oi < idxl)) { val = ov; idxl = oi; }
        }
        if (lane == idxl) { dst[j*3+0] = px; dst[j*3+1] = py; dst[j*3+2] = pz; }
        last = idxl;
    }
}

// ---------- kernel 5: displacement MLP (3->32->16->3) + residual -> q2 ----------
__global__ void k_mlp(const float* __restrict__ ndp,
                      const float* __restrict__ wd1, const float* __restrict__ gd1, const float* __restrict__ bd1,
                      const float* __restrict__ wd2, const float* __restrict__ gd2, const float* __restrict__ bd2,
                      const float* __restrict__ wd3, const float* __restrict__ gd3, const float* __restrict__ bd3,
                      float* __restrict__ q2)
{
    __shared__ float W1[96], S1[32], B1s[32], W2[512], S2[16], B2s[16], W3[48], S3[3], B3s[3];
    int tid = threadIdx.x;
    const float inv = sqrtf(1.00001f);
    for (int i = tid; i < 96;  i += blockDim.x) W1[i]=wd1[i];
    for (int i = tid; i < 512; i += blockDim.x) W2[i]=wd2[i];
    for (int i = tid; i < 48;  i += blockDim.x) W3[i]=wd3[i];
    if (tid < 32) { S1[tid]=gd1[tid]/inv; B1s[tid]=bd1[tid]; }
    if (tid >= 32 && tid < 48) { int c=tid-32; S2[c]=gd2[c]/inv; B2s[c]=bd2[c]; }
    if (tid >= 48 && tid < 51) { int c=tid-48; S3[c]=gd3[c]/inv; B3s[c]=bd3[c]; }
    __syncthreads();
    int t = blockIdx.x*blockDim.x + tid;   // 196608 exact
    int k = t % KK, n = (t/KK)%NN, b = t/(NN*KK);
    size_t base = (((size_t)b*3)*NN + n)*KK + k;
    float x0 = ndp[base], x1 = ndp[base + NKK], x2 = ndp[base + 2*(size_t)NKK];
    float h1[32];
    #pragma unroll
    for (int o = 0; o < 32; ++o)
        h1[o] = relu_((W1[o*3+0]*x0 + W1[o*3+1]*x1 + W1[o*3+2]*x2)*S1[o] + B1s[o]);
    float h2[16];
    #pragma unroll
    for (int o = 0; o < 16; ++o) {
        float a = 0.f;
        #pragma unroll
        for (int c = 0; c < 32; ++c) a += W2[o*32+c]*h1[c];
        h2[o] = relu_(a*S2[o] + B2s[o]);
    }
    float xv[3] = {x0, x1, x2};
    #pragma unroll
    for (int d = 0; d < 3; ++d) {
        float a = 0.f;
        #pragma unroll
        for (int c = 0; c < 16; ++c) a += W3[d*16+c]*h2[c];
        q2[base + (size_t)d*NKK] = xv[d] + (a*S3[d] + B3s[d]);
    }
}

// ---------- kernel 6: ball query 2 (k=1) + dp2 = s2[j2] - q2 ----------
__global__ void k_bq2(const float* __restrict__ dpf, const float* __restrict__ q2f,
                      int* __restrict__ idx2, float* __restrict__ dp2)
{
    int t = blockIdx.x*blockDim.x + threadIdx.x;   // 196608 exact
    int g = t / KK, kq = t % KK;
    const float* srow = dpf + (size_t)g*72;
    const float* qp   = q2f + (size_t)g*72 + kq*3;
    float qx=qp[0], qy=qp[1], qz=qp[2];
    float sq = qx*qx + qy*qy + qz*qz;
    const float rsq = (float)(0.15*0.15);
    int j2 = 0;
    for (int s = 0; s < KK; ++s) {
        float sx=srow[s*3+0], sy=srow[s*3+1], sz=srow[s*3+2];
        float ss  = sx*sx + sy*sy + sz*sz;
        float dot = qx*sx + qy*sy + qz*sz;
        float d2 = (sq + ss) - 2.0f*dot;
        if (d2 < rsq) { j2 = s; break; }
    }
    idx2[t] = j2;
    float* drow = dp2 + (size_t)g*72;
    drow[0*KK + kq] = srow[j2*3+0] - qx;
    drow[1*KK + kq] = srow[j2*3+1] - qy;
    drow[2*KK + kq] = srow[j2*3+2] - qz;
}

// ---------- kernel 7: fused gather + MFMA (D = F*ww^T) + fragment epilogue ----------
// Lane l: l15=l&15 -> o-col, lh=l>>4 -> colIdx group. acc[ot][t][r] = D[colIdx=16t+4lh+r][o=(2wv+ot)*16+l15].
// Softmax over k per (n,o): per-lane partials + masked shfl_xor(16/32) butterfly over lh.
__global__ __launch_bounds__(256, 6) void k_final(
    const float* __restrict__ f1T, const int* __restrict__ idx, const int* __restrict__ idx2,
    const float* __restrict__ dp2, const unsigned short* __restrict__ wwAbf,
    const float* __restrict__ gw, const float* __restrict__ bw,
    const float* __restrict__ wc2, const float* __restrict__ gc2, const float* __restrict__ bc2,
    float* __restrict__ fout, float* __restrict__ pe)
{
    __shared__ unsigned short Gs[2*128*26];   // bf16 staging [nl][c][kk], stride 26 (13.3 KB)
    __shared__ unsigned short Fbf[48*128];    // bf16 [col][c], byte ^= (col&7)<<4 (12.3 KB)
    __shared__ float Ds[2][3][KK];
    __shared__ int   IRs[2][KK];
    int tid = threadIdx.x;
    int bid = blockIdx.x;
    int b = bid >> 11;
    int n0 = (bid & 2047)*2;
    const float inv = sqrtf(1.00001f);

    if (tid < 48) {
        int nl = tid/24, kk = tid%24;
        IRs[nl][kk] = idx[((size_t)b*NN + (n0+nl))*KK + kk];
    }
    if (tid >= 64 && tid < 208) {
        int u = tid-64; int nl = u/72, r = u%72, d = r/24, k = r%24;
        Ds[nl][d][k] = dp2[(((size_t)b*3 + d)*NN + (n0+nl))*KK + k];
    }
    int c = tid & 127, kh = tid >> 7;
    __syncthreads();                        // barrier 1 (IRs, Ds ready)

    // gather both n tiles -> bf16 staging
    const float* basep = f1T + (size_t)b*NN*CO + c;
    #pragma unroll
    for (int nl = 0; nl < 2; ++nl)
        #pragma unroll
        for (int j = 0; j < 12; ++j) {
            int kk = kh*12 + j;
            Gs[nl*3328 + c*26 + kk] = f2bf(basep[(size_t)IRs[nl][kk]*CO]);
        }
    __syncthreads();                        // barrier 2

    // permute both (idx2 loaded here, transient)
    {
        int g = (b*CO + c)*32 + (n0 >> 7);
        const int4* i4 = (const int4*)(idx2 + (size_t)g*KK) + kh*3;
        int4 ia = i4[0], ib = i4[1], ic = i4[2];
        int i2r[12] = {ia.x,ia.y,ia.z,ia.w, ib.x,ib.y,ib.z,ib.w, ic.x,ic.y,ic.z,ic.w};
        #pragma unroll
        for (int nl = 0; nl < 2; ++nl)
            #pragma unroll
            for (int j = 0; j < 12; ++j) {
                int col = nl*24 + kh*12 + j;
                unsigned int boff = (unsigned)((col*256 + c*2) ^ ((col&7)<<4));
                *(unsigned short*)((char*)Fbf + boff) = Gs[nl*3328 + c*26 + i2r[j]];
            }
    }

    // pe phase (independent of MFMA): old mapping, compute pev + store, discard
    {
        int op = (tid & 127) >> 1, half = tid & 1, nl = tid >> 7;
        int k0 = half*12, o0 = op*2, n = n0 + nl;
        float wa0=wc2[o0*3], wa1=wc2[o0*3+1], wa2=wc2[o0*3+2];
        float wb0=wc2[o0*3+3], wb1=wc2[o0*3+4], wb2=wc2[o0*3+5];
        float sca = gc2[o0]/inv,   bca = bc2[o0];
        float scb = gc2[o0+1]/inv, bcb = bc2[o0+1];
        float* pr0 = pe + (((size_t)b*CO + o0)*NN + n)*KK + k0;
        float* pr1 = pe + (((size_t)b*CO + o0+1)*NN + n)*KK + k0;
        #pragma unroll
        for (int q4 = 0; q4 < 3; ++q4) {
            float4 v0, v1;
            #pragma unroll
            for (int e = 0; e < 4; ++e) {
                int k = k0 + q4*4 + e;
                float d0 = Ds[nl][0][k], d1 = Ds[nl][1][k], d2 = Ds[nl][2][k];
                float pa = relu_((wa0*d0 + wa1*d1 + wa2*d2)*sca + bca);
                float pb = relu_((wb0*d0 + wb1*d1 + wb2*d2)*scb + bcb);
                (&v0.x)[e] = pa; (&v1.x)[e] = pb;
            }
            ((float4*)pr0)[q4] = v0;
            ((float4*)pr1)[q4] = v1;
        }
    }

    // ww B-fragments
    int wv = tid >> 6, l = tid & 63;
    const short8* wwA8 = (const short8*)wwAbf;
    short8 Wf[2][4];
    #pragma unroll
    for (int ot = 0; ot < 2; ++ot)
        #pragma unroll
        for (int ks = 0; ks < 4; ++ks)
            Wf[ot][ks] = wwA8[((wv*2 + ot)*4 + ks)*64 + l];
    __syncthreads();                        // barrier 3 (Fbf ready)

    int l15 = l & 15, lh = l >> 4;
    f32x4 acc[2][3];
    #pragma unroll
    for (int ot=0;ot<2;++ot)
        #pragma unroll
        for (int t=0;t<3;++t)
            acc[ot][t] = (f32x4){0.f,0.f,0.f,0.f};
    #pragma unroll
    for (int t = 0; t < 3; ++t) {
        int row = t*16 + l15;
        #pragma unroll
        for (int ks = 0; ks < 4; ++ks) {
            unsigned int boff = (unsigned)((row*256 + (ks*32 + lh*8)*2) ^ ((row&7)<<4));
            short8 Afr = *(const short8*)((const char*)Fbf + boff);
            acc[0][t] = __builtin_amdgcn_mfma_f32_16x16x32_bf16(Afr, Wf[0][ks], acc[0][t], 0,0,0);
            acc[1][t] = __builtin_amdgcn_mfma_f32_16x16x32_bf16(Afr, Wf[1][ks], acc[1][t], 0,0,0);
        }
    }

    // Ds fragments (ot-independent): t0 -> n0 k=4lh+r; t1 -> lh<2 ? n0 k=16+4lh+r : n1 k=4(lh-2)+r; t2 -> n1 k=8+4lh+r
    f32x4 Da[3], Db[3], Dc[3];
    #pragma unroll
    for (int d = 0; d < 3; ++d) {
        Da[d] = *(const f32x4*)&Ds[0][d][4*lh];
        Db[d] = (lh < 2) ? *(const f32x4*)&Ds[0][d][16 + 4*lh]
                         : *(const f32x4*)&Ds[1][d][4*(lh-2)];
        Dc[d] = *(const f32x4*)&Ds[1][d][8 + 4*lh];
    }

    #pragma unroll
    for (int ot = 0; ot < 2; ++ot) {
        int o = (2*wv + ot)*16 + l15;
        float sw = gw[o]/inv, bwv = bw[o];
        float L0[4], L1[4], L2[4];
        #pragma unroll
        for (int r=0;r<4;++r){
            L0[r] = acc[ot][0][r]*sw + bwv;
            L1[r] = acc[ot][1][r]*sw + bwv;
            L2[r] = acc[ot][2][r]*sw + bwv;
        }
        float m0 = fmaxf(fmaxf(L0[0],L0[1]), fmaxf(L0[2],L0[3]));
        float m1 = fmaxf(fmaxf(L2[0],L2[1]), fmaxf(L2[2],L2[3]));
        float mt = fmaxf(fmaxf(L1[0],L1[1]), fmaxf(L1[2],L1[3]));
        if (lh < 2) m0 = fmaxf(m0, mt); else m1 = fmaxf(m1, mt);
        m0 = fmaxf(m0, __shfl_xor(m0, 16)); m0 = fmaxf(m0, __shfl_xor(m0, 32));
        m1 = fmaxf(m1, __shfl_xor(m1, 16)); m1 = fmaxf(m1, __shfl_xor(m1, 32));
        float mt1 = (lh < 2) ? m0 : m1;
        float e0[4], e1[4], e2[4];
        float s0 = 0.f, s1 = 0.f, st = 0.f;
        #pragma unroll
        for (int r=0;r<4;++r){
            e0[r] = __expf(L0[r]-m0);  s0 += e0[r];
            e2[r] = __expf(L2[r]-m1);  s1 += e2[r];
            e1[r] = __expf(L1[r]-mt1); st += e1[r];
        }
        if (lh < 2) s0 += st; else s1 += st;
        s0 += __shfl_xor(s0, 16); s0 += __shfl_xor(s0, 32);
        s1 += __shfl_xor(s1, 16); s1 += __shfl_xor(s1, 32);
        float rs0 = 1.0f/s0, rs1 = 1.0f/s1;
        float rst = (lh < 2) ? rs0 : rs1;
        float wa0=wc2[o*3], wa1=wc2[o*3+1], wa2=wc2[o*3+2];
        float sca = gc2[o]/inv, bca = bc2[o];
        float fo0 = -3.4e38f, fo1 = -3.4e38f;
        #pragma unroll
        for (int r=0;r<4;++r){
            // t0 (n0)
            {
                float pv = relu_((wa0*Da[0][r] + wa1*Da[1][r] + wa2*Da[2][r])*sca + bca);
                int ci = 4*lh + r;
                unsigned int boff = (unsigned)((ci*256 + o*2) ^ ((ci&7)<<4));
                float fj = bfbits2f(*(const unsigned short*)((const char*)Fbf + boff));
                fo0 = fmaxf(fo0, (pv + fj)*e0[r]*rs0);
            }
            // t1 (n0 for lh<2, n1 for lh>=2)
            {
                float pv = relu_((wa0*Db[0][r] + wa1*Db[1][r] + wa2*Db[2][r])*sca + bca);
                int ci = 16 + 4*lh + r;
                unsigned int boff = (unsigned)((ci*256 + o*2) ^ ((ci&7)<<4));
                float fj = bfbits2f(*(const unsigned short*)((const char*)Fbf + boff));
                float v = (pv + fj)*e1[r]*rst;
                if (lh < 2) fo0 = fmaxf(fo0, v); else fo1 = fmaxf(fo1, v);
            }
            // t2 (n1)
            {
                float pv = relu_((wa0*Dc[0][r] + wa1*Dc[1][r] + wa2*Dc[2][r])*sca + bca);
                int ci = 32 + 4*lh + r;
                unsigned int boff = (unsigned)((ci*256 + o*2) ^ ((ci&7)<<4));
                float fj = bfbits2f(*(const unsigned short*)((const char*)Fbf + boff));
                fo1 = fmaxf(fo1, (pv + fj)*e2[r]*rs1);
            }
        }
        fo0 = fmaxf(fo0, __shfl_xor(fo0, 16)); fo0 = fmaxf(fo0, __shfl_xor(fo0, 32));
        fo1 = fmaxf(fo1, __shfl_xor(fo1, 16)); fo1 = fmaxf(fo1, __shfl_xor(fo1, 32));
        if (lh == 0) {
            float2 fv; fv.x = fo0; fv.y = fo1;
            *(float2*)&fout[((size_t)b*CO + o)*NN + n0] = fv;
        }
    }
}

extern "C" void kernel_launch(void* const* d_in, const int* in_sizes, int n_in,
                              void* d_out, int out_size, void* d_ws, size_t ws_size,
                              hipStream_t stream)
{
    const float* pc  = (const float*)d_in[0];
    const float* f   = (const float*)d_in[1];
    const float* w1  = (const float*)d_in[3];
    const float* g1  = (const float*)d_in[4];
    const float* b1  = (const float*)d_in[5];
    const float* wd1 = (const float*)d_in[6];
    const float* gd1 = (const float*)d_in[7];
    const float* bd1 = (const float*)d_in[8];
    const float* wd2 = (const float*)d_in[9];
    const float* gd2 = (const float*)d_in[10];
    const float* bd2 = (const float*)d_in[11];
    const float* wd3 = (const float*)d_in[12];
    const float* gd3 = (const float*)d_in[13];
    const float* bd3 = (const float*)d_in[14];
    const float* ww  = (const float*)d_in[15];
    const float* gw  = (const float*)d_in[16];
    const float* bw  = (const float*)d_in[17];
    const float* wc2 = (const float*)d_in[18];
    const float* gc2 = (const float*)d_in[19];
    const float* bc2 = (const float*)d_in[20];

    float* out     = (float*)d_out;
    float* outPc   = out;                               // 49152
    float* outFout = out + 49152;                       // 1048576
    float* outPe   = out + 49152 + 1048576;             // 25165824

    char* ws = (char*)d_ws;
    size_t off = 0;
    auto alloc = [&](size_t bytes)->void* {
        void* q = ws + off; off += (bytes + 255) & ~(size_t)255; return q;
    };
    float* p    = (float*)alloc((size_t)GQ*3*4);
    float* pS   = (float*)alloc((size_t)GQ*3*4);
    float* f1T  = (float*)alloc((size_t)BB*NN*CO*4);
    int*   idx  = (int*)  alloc((size_t)BB*NN*KK*4);
    float* dpf  = (float*)alloc((size_t)BB*3*NN*KK*4);
    float* ndp  = (float*)alloc((size_t)BB*3*NN*KK*4);
    float* q2f  = (float*)alloc((size_t)BB*3*NN*KK*4);
    int*   idx2 = (int*)  alloc((size_t)GQ*KK*4);
    float* dp2  = (float*)alloc((size_t)GQ*72*4);
    unsigned short* wwAbf = (unsigned short*)alloc((size_t)CO*CO*2);

    k_f1   <<<dim3(512), dim3(256), 0, stream>>>(f, w1, g1, b1, pc, ww, f1T, outPc, p, pS, wwAbf);
    k_bq1  <<<dim3(GQ/4), dim3(256), 0, stream>>>(pS, idx);
    k_geo  <<<dim3(GQ/8), dim3(256), 0, stream>>>(p, idx, dpf, ndp);
    k_mlp  <<<dim3((BB*NN*KK)/256), dim3(256), 0, stream>>>(ndp, wd1,gd1,bd1, wd2,gd2,bd2, wd3,gd3,bd3, q2f);
    k_bq2  <<<dim3((GQ*KK)/256), dim3(256), 0, stream>>>(dpf, q2f, idx2, dp2);
    k_final<<<dim3(BB*NN/2), dim3(256), 0, stream>>>(f1T, idx, idx2, dp2, wwAbf, gw, bw, wc2, gc2, bc2, outFout, outPe);
}

// Round 8
// 121.442 us; speedup vs baseline: 1.1049x; 1.1049x over previous
//
#include <hip/hip_runtime.h>
#include <stdint.h>

// SetAbstraction forward, MI355X. B=2, N=4096, CIN=64, COUT=128, K=24.
// R8: k_final reverted to R6 structure (4-barrier dual-n gather, M-in-LDS, proven fast);
// single new change: bijective XCD-chunked blockIdx swizzle so adjacent n-pairs
// (co-writers of shared pe cache lines) colocate on one XCD L2. R7's fragment-epilogue
// restructure doubled HBM write traffic (200MB) -> reverted.

#define BB 2
#define NN 4096
#define CI 64
#define CO 128
#define KK 24
#define GQ (BB*NN)        // 8192
#define NKK (NN*KK)       // 98304

typedef __attribute__((ext_vector_type(8))) short short8;
typedef __attribute__((ext_vector_type(4))) float f32x4;

__device__ __forceinline__ float relu_(float x){ return fmaxf(x, 0.0f); }
__device__ __forceinline__ unsigned short f2bf(float x){
    unsigned int u = __float_as_uint(x);
    return (unsigned short)((u + 0x7FFFu + ((u>>16)&1u)) >> 16);
}

// ---------- kernel 1: f1T[b][n][o] = relu(bn(w1 @ f)) + prep ----------
__global__ __launch_bounds__(256) void k_f1(const float* __restrict__ f, const float* __restrict__ w1,
                     const float* __restrict__ g1, const float* __restrict__ b1,
                     const float* __restrict__ pc, const float* __restrict__ ww,
                     float* __restrict__ f1T, float* __restrict__ outPc,
                     float* __restrict__ p, float* __restrict__ pS,
                     unsigned short* __restrict__ wwAbf)
{
    int tid = threadIdx.x;
    int bid = blockIdx.x;
    {   // prep (grid 512 covers 49152 and 16384)
        int t = bid*256 + tid;
        if (t < BB*NN*6) {
            float v = pc[t];
            outPc[t] = v;
            int d = t % 6;
            if (d < 3) {
                int q = t/6;
                p[q*3 + d] = v;
                pS[d*GQ + q] = v;       // SoA: pS[d][b*4096+n]
            }
        }
        if (t < CO*CO) {
            int o = t >> 7, c = t & 127;
            int otile = o >> 4, m = o & 15;
            int ks = c >> 5, kk = c & 31;
            int lane = m | ((kk >> 3) << 4);
            int j = kk & 7;
            wwAbf[(((otile*4 + ks)*64 + lane)<<3) + j] = f2bf(ww[t]);
        }
    }
    __shared__ float W[CI*129];
    __shared__ float ft[CI*16];
    for (int i = tid; i < CI*CO; i += 256) {
        int o = i >> 6, c = i & 63;
        W[c*129 + o] = w1[i];
    }
    int b = bid >> 8;
    int n0 = (bid & 255) * 16;
    {
        int c = tid >> 2, nn = (tid & 3) * 4;
        float4 v = *(const float4*)(f + (size_t)b*CI*NN + (size_t)c*NN + n0 + nn);
        *(float4*)&ft[c*16 + nn] = v;
    }
    __syncthreads();
    int o = tid & 127, g = tid >> 7;
    float acc[8];
    #pragma unroll
    for (int j = 0; j < 8; ++j) acc[j] = 0.f;
    const float* ftg = ft + g*8;
    #pragma unroll 8
    for (int c = 0; c < CI; ++c) {
        float w = W[c*129 + o];
        float4 fa = *(const float4*)&ftg[c*16];
        float4 fb4 = *(const float4*)&ftg[c*16 + 4];
        acc[0] += w*fa.x;  acc[1] += w*fa.y;  acc[2] += w*fa.z;  acc[3] += w*fa.w;
        acc[4] += w*fb4.x; acc[5] += w*fb4.y; acc[6] += w*fb4.z; acc[7] += w*fb4.w;
    }
    float sc = g1[o] / sqrtf(1.00001f);
    float bo = b1[o];
    #pragma unroll
    for (int j = 0; j < 8; ++j) {
        int n = n0 + g*8 + j;
        f1T[((size_t)b*NN + n)*CO + o] = relu_(acc[j]*sc + bo);
    }
}

// ---------- kernel 2: ball query 1 -> idx (B,N,K), SoA point loads ----------
__global__ void k_bq1(const float* __restrict__ pS, int* __restrict__ idx)
{
    int wave = threadIdx.x >> 6;
    int lane = threadIdx.x & 63;
    int q = blockIdx.x*4 + wave;          // 0..8191
    int b = q >> 12;
    int n = q & 4095;
    int boff = b << 12;
    const float* Sx = pS + boff;
    const float* Sy = pS + GQ + boff;
    const float* Sz = pS + 2*GQ + boff;
    float qx = Sx[n], qy = Sy[n], qz = Sz[n];
    float sq = qx*qx + qy*qy + qz*qz;
    const float rsq = (float)(0.15*0.15);
    int cnt = 0, first = 0;
    int* orow = idx + (size_t)q*KK;
    for (int chunk = 0; chunk < 64; ++chunk) {
        int s = chunk*64 + lane;
        float sx = Sx[s], sy = Sy[s], sz = Sz[s];
        float ss  = sx*sx + sy*sy + sz*sz;
        float dot = qx*sx + qy*sy + qz*sz;
        float d2 = (sq + ss) - 2.0f*dot;
        unsigned long long m = __ballot(d2 < rsq);
        while (m && cnt < KK) {
            int pos = __ffsll((unsigned long long)m) - 1;
            int sidx = chunk*64 + pos;
            if (cnt == 0) first = sidx;
            if (lane == 0) orow[cnt] = sidx;
            ++cnt;
            m &= m - 1;
        }
        if (cnt >= KK) break;
    }
    if (lane == 0)
        for (int j = cnt; j < KK; ++j) orow[j] = first;
}

// ---------- kernel 3: fused mkdp + FPS (k_geo) ----------
__global__ __launch_bounds__(256) void k_geo(const float* __restrict__ p, const int* __restrict__ idx,
                                             float* __restrict__ dpf, float* __restrict__ ndp)
{
    int tid = threadIdx.x;
    int lane = tid & 31;                 // = k
    int row = blockIdx.x*8 + (tid >> 5); // grid 1024
    float px = 0.f, py = 0.f, pz = 0.f, dist;
    if (lane < KK) {
        float v[3];
        #pragma unroll
        for (int d = 0; d < 3; ++d) {
            int u = 3*lane + d;          // 0..71
            int qq = u / 24;             // 0..2
            int kk = u - qq*24;
            int m = row*3 + qq;          // block index in (B,3,N) blocks of 24
            int b = (m >= 3*NN) ? 1 : 0;
            int rem = m - b*3*NN;
            int dd = rem >> 12;          // /4096
            int n = rem & 4095;
            int base = (b << 12);
            int j = idx[((size_t)(base + n))*KK + kk];
            v[d] = p[(base + j)*3 + dd] - p[(base + n)*3 + dd];
        }
        px = v[0]; py = v[1]; pz = v[2];
        dist = 1e10f;
        float* drow = dpf + (size_t)row*72 + lane*3;
        drow[0] = px; drow[1] = py; drow[2] = pz;
    } else {
        dist = -3.4e38f;                 // idle lanes never win argmax
    }
    float* dst = ndp + (size_t)row*72;
    if (lane == 0) { dst[0] = px; dst[1] = py; dst[2] = pz; }
    int last = 0;
    for (int j = 1; j < KK; ++j) {
        float lx = __shfl(px, last, 32);
        float ly = __shfl(py, last, 32);
        float lz = __shfl(pz, last, 32);
        float dx = px-lx, dy = py-ly, dz = pz-lz;
        float d = dx*dx + dy*dy + dz*dz;
        dist = fminf(dist, d);
        float val = dist; int idxl = lane;
        #pragma unroll
        for (int off = 16; off > 0; off >>= 1) {
            float ov = __shfl_xor(val, off, 32);
            int   oi = __shfl_xor(idxl, off, 32);
            if (ov > val || (ov == val && oi < idxl)) { val = ov; idxl = oi; }
        }
        if (lane == idxl) { dst[j*3+0] = px; dst[j*3+1] = py; dst[j*3+2] = pz; }
        last = idxl;
    }
}

// ---------- kernel 5: displacement MLP (3->32->16->3) + residual -> q2 ----------
__global__ void k_mlp(const float* __restrict__ ndp,
                      const float* __restrict__ wd1, const float* __restrict__ gd1, const float* __restrict__ bd1,
                      const float* __restrict__ wd2, const float* __restrict__ gd2, const float* __restrict__ bd2,
                      const float* __restrict__ wd3, const float* __restrict__ gd3, const float* __restrict__ bd3,
                      float* __restrict__ q2)
{
    __shared__ float W1[96], S1[32], B1s[32], W2[512], S2[16], B2s[16], W3[48], S3[3], B3s[3];
    int tid = threadIdx.x;
    const float inv = sqrtf(1.00001f);
    for (int i = tid; i < 96;  i += blockDim.x) W1[i]=wd1[i];
    for (int i = tid; i < 512; i += blockDim.x) W2[i]=wd2[i];
    for (int i = tid; i < 48;  i += blockDim.x) W3[i]=wd3[i];
    if (tid < 32) { S1[tid]=gd1[tid]/inv; B1s[tid]=bd1[tid]; }
    if (tid >= 32 && tid < 48) { int c=tid-32; S2[c]=gd2[c]/inv; B2s[c]=bd2[c]; }
    if (tid >= 48 && tid < 51) { int c=tid-48; S3[c]=gd3[c]/inv; B3s[c]=bd3[c]; }
    __syncthreads();
    int t = blockIdx.x*blockDim.x + tid;   // 196608 exact
    int k = t % KK, n = (t/KK)%NN, b = t/(NN*KK);
    size_t base = (((size_t)b*3)*NN + n)*KK + k;
    float x0 = ndp[base], x1 = ndp[base + NKK], x2 = ndp[base + 2*(size_t)NKK];
    float h1[32];
    #pragma unroll
    for (int o = 0; o < 32; ++o)
        h1[o] = relu_((W1[o*3+0]*x0 + W1[o*3+1]*x1 + W1[o*3+2]*x2)*S1[o] + B1s[o]);
    float h2[16];
    #pragma unroll
    for (int o = 0; o < 16; ++o) {
        float a = 0.f;
        #pragma unroll
        for (int c = 0; c < 32; ++c) a += W2[o*32+c]*h1[c];
        h2[o] = relu_(a*S2[o] + B2s[o]);
    }
    float xv[3] = {x0, x1, x2};
    #pragma unroll
    for (int d = 0; d < 3; ++d) {
        float a = 0.f;
        #pragma unroll
        for (int c = 0; c < 16; ++c) a += W3[d*16+c]*h2[c];
        q2[base + (size_t)d*NKK] = xv[d] + (a*S3[d] + B3s[d]);
    }
}

// ---------- kernel 6: ball query 2 (k=1) + dp2 = s2[j2] - q2 ----------
__global__ void k_bq2(const float* __restrict__ dpf, const float* __restrict__ q2f,
                      int* __restrict__ idx2, float* __restrict__ dp2)
{
    int t = blockIdx.x*blockDim.x + threadIdx.x;   // 196608 exact
    int g = t / KK, kq = t % KK;
    const float* srow = dpf + (size_t)g*72;
    const float* qp   = q2f + (size_t)g*72 + kq*3;
    float qx=qp[0], qy=qp[1], qz=qp[2];
    float sq = qx*qx + qy*qy + qz*qz;
    const float rsq = (float)(0.15*0.15);
    int j2 = 0;
    for (int s = 0; s < KK; ++s) {
        float sx=srow[s*3+0], sy=srow[s*3+1], sz=srow[s*3+2];
        float ss  = sx*sx + sy*sy + sz*sz;
        float dot = qx*sx + qy*sy + qz*sz;
        float d2 = (sq + ss) - 2.0f*dot;
        if (d2 < rsq) { j2 = s; break; }
    }
    idx2[t] = j2;
    float* drow = dp2 + (size_t)g*72;
    drow[0*KK + kq] = srow[j2*3+0] - qx;
    drow[1*KK + kq] = srow[j2*3+1] - qy;
    drow[2*KK + kq] = srow[j2*3+2] - qz;
}

// ---------- kernel 7: fused gather + MFMA conv + softmax + pe + fout ----------
// R8: R6 structure + XCD-chunked bid swizzle (4096 wgs, 8 XCDs, 512/XCD).
__global__ __launch_bounds__(256, 4) void k_final(
    const float* __restrict__ f1T, const int* __restrict__ idx, const int* __restrict__ idx2,
    const float* __restrict__ dp2, const unsigned short* __restrict__ wwAbf,
    const float* __restrict__ gw, const float* __restrict__ bw,
    const float* __restrict__ wc2, const float* __restrict__ gc2, const float* __restrict__ bc2,
    float* __restrict__ fout, float* __restrict__ pe)
{
    __shared__ float GM[6400];              // union: G[nl][c][kk] (2*128*25) | M[col][o] stride132 (6336)
    __shared__ unsigned short Fbf[48*128];  // bf16 [col][c], byte ^= (col&7)<<4
    __shared__ float Ds[2][3][KK];
    __shared__ int   IRs[2][KK];
    int tid = threadIdx.x;
    int bid0 = blockIdx.x;
    int bid = ((bid0 & 7) << 9) | (bid0 >> 3);   // bijective XCD swizzle (4096 % 8 == 0)
    int b = bid >> 11;
    int n0 = (bid & 2047)*2;

    if (tid < 48) {
        int nl = tid/24, kk = tid%24;
        IRs[nl][kk] = idx[((size_t)b*NN + (n0+nl))*KK + kk];
    }
    if (tid >= 64 && tid < 208) {
        int u = tid-64; int nl = u/72, r = u%72, d = r/24, k = r%24;
        Ds[nl][d][k] = dp2[(((size_t)b*3 + d)*NN + (n0+nl))*KK + k];
    }
    int c = tid & 127, kh = tid >> 7;
    int i2r[12];
    {
        int g = (b*CO + c)*32 + (n0 >> 7);
        const int4* i4 = (const int4*)(idx2 + (size_t)g*KK) + kh*3;
        int4 a = i4[0], bq = i4[1], cq4 = i4[2];
        i2r[0]=a.x; i2r[1]=a.y; i2r[2]=a.z; i2r[3]=a.w;
        i2r[4]=bq.x; i2r[5]=bq.y; i2r[6]=bq.z; i2r[7]=bq.w;
        i2r[8]=cq4.x; i2r[9]=cq4.y; i2r[10]=cq4.z; i2r[11]=cq4.w;
    }
    int wv = tid >> 6, l = tid & 63;
    const short8* wwA8 = (const short8*)wwAbf;
    short8 Af[2][4];
    #pragma unroll
    for (int ot = 0; ot < 2; ++ot)
        #pragma unroll
        for (int ks = 0; ks < 4; ++ks)
            Af[ot][ks] = wwA8[((wv*2 + ot)*4 + ks)*64 + l];
    __syncthreads();                        // barrier 1 (IRs ready)

    // gather BOTH n tiles
    const float* basep = f1T + (size_t)b*NN*CO + c;
    #pragma unroll
    for (int nl = 0; nl < 2; ++nl)
        #pragma unroll
        for (int j = 0; j < 12; ++j) {
            int kk = kh*12 + j;
            GM[nl*3200 + c*25 + kk] = basep[(size_t)IRs[nl][kk]*CO];
        }
    __syncthreads();                        // barrier 2

    // permute both
    #pragma unroll
    for (int nl = 0; nl < 2; ++nl)
        #pragma unroll
        for (int j = 0; j < 12; ++j) {
            int col = nl*24 + kh*12 + j;
            unsigned int boff = (unsigned)((col*256 + c*2) ^ ((col&7)<<4));
            *(unsigned short*)((char*)Fbf + boff) = f2bf(GM[nl*3200 + c*25 + i2r[j]]);
        }
    __syncthreads();                        // barrier 3 (all G reads done -> GM reusable as M)

    {
        f32x4 acc[2][3];
        #pragma unroll
        for (int ot=0;ot<2;++ot)
            #pragma unroll
            for (int ct=0;ct<3;++ct)
                acc[ot][ct] = (f32x4){0.f,0.f,0.f,0.f};
        int row_l = l & 15, kc_l = (l >> 4) << 3;
        #pragma unroll
        for (int ct = 0; ct < 3; ++ct) {
            int row = ct*16 + row_l;
            #pragma unroll
            for (int ks = 0; ks < 4; ++ks) {
                unsigned int boff = (unsigned)((row*256 + (ks*32 + kc_l)*2) ^ ((row&7)<<4));
                short8 Bf = *(const short8*)((const char*)Fbf + boff);
                acc[0][ct] = __builtin_amdgcn_mfma_f32_16x16x32_bf16(Af[0][ks], Bf, acc[0][ct], 0,0,0);
                acc[1][ct] = __builtin_amdgcn_mfma_f32_16x16x32_bf16(Af[1][ks], Bf, acc[1][ct], 0,0,0);
            }
        }
        #pragma unroll
        for (int ot = 0; ot < 2; ++ot) {
            int o = wv*32 + ot*16 + ((l>>4)<<2);
            #pragma unroll
            for (int ct = 0; ct < 3; ++ct) {
                int col = ct*16 + (l & 15);
                *(f32x4*)&GM[col*132 + o] = acc[ot][ct];
            }
        }
    }
    __syncthreads();                        // barrier 4 (M ready)

    int op = (tid & 127) >> 1, half = tid & 1, nl = tid >> 7;
    int k0 = half*12;
    int o0 = op*2;
    int n  = n0 + nl;
    int colb = nl*24 + k0;
    float a0[12], a1[12];
    #pragma unroll
    for (int j = 0; j < 12; ++j) {
        float2 m2 = *(const float2*)&GM[(colb+j)*132 + o0];
        a0[j] = m2.x; a1[j] = m2.y;
    }
    const float inv = sqrtf(1.00001f);
    float sw0 = gw[o0]/inv,   bw0 = bw[o0];
    float sw1 = gw[o0+1]/inv, bw1 = bw[o0+1];
    float pev0[12], pev1[12];
    {
        float wa0=wc2[o0*3], wa1=wc2[o0*3+1], wa2=wc2[o0*3+2];
        float wb0=wc2[o0*3+3], wb1=wc2[o0*3+4], wb2=wc2[o0*3+5];
        float sca = gc2[o0]/inv,   bca = bc2[o0];
        float scb = gc2[o0+1]/inv, bcb = bc2[o0+1];
        #pragma unroll
        for (int j = 0; j < 12; ++j) {
            float d0 = Ds[nl][0][k0+j], d1 = Ds[nl][1][k0+j], d2 = Ds[nl][2][k0+j];
            pev0[j] = relu_((wa0*d0 + wa1*d1 + wa2*d2)*sca + bca);
            pev1[j] = relu_((wb0*d0 + wb1*d1 + wb2*d2)*scb + bcb);
        }
    }
    float m0 = -3.4e38f, m1 = -3.4e38f;
    #pragma unroll
    for (int j=0;j<12;++j){
        a0[j] = a0[j]*sw0 + bw0; m0 = fmaxf(m0, a0[j]);
        a1[j] = a1[j]*sw1 + bw1; m1 = fmaxf(m1, a1[j]);
    }
    m0 = fmaxf(m0, __shfl_xor(m0, 1));
    m1 = fmaxf(m1, __shfl_xor(m1, 1));
    float s0 = 0.f, s1 = 0.f;
    #pragma unroll
    for (int j=0;j<12;++j){
        a0[j] = __expf(a0[j]-m0); s0 += a0[j];
        a1[j] = __expf(a1[j]-m1); s1 += a1[j];
    }
    s0 += __shfl_xor(s0, 1);
    s1 += __shfl_xor(s1, 1);
    float rs0 = 1.0f/s0, rs1 = 1.0f/s1;
    float fo0 = -3.4e38f, fo1 = -3.4e38f;
    #pragma unroll
    for (int j=0;j<12;++j){
        unsigned int boff = (unsigned)(((colb+j)*256 + o0*2) ^ (((colb+j)&7)<<4));
        unsigned int v = *(const unsigned int*)((const char*)Fbf + boff);
        float fj0 = __uint_as_float((v & 0xffffu) << 16);
        float fj1 = __uint_as_float((v >> 16) << 16);
        fo0 = fmaxf(fo0, (pev0[j] + fj0)*a0[j]*rs0);
        fo1 = fmaxf(fo1, (pev1[j] + fj1)*a1[j]*rs1);
    }
    fo0 = fmaxf(fo0, __shfl_xor(fo0, 1));
    fo1 = fmaxf(fo1, __shfl_xor(fo1, 1));
    fout[((size_t)b*CO + o0+half)*NN + n] = half ? fo1 : fo0;
    float* pr0 = pe + (((size_t)b*CO + o0)*NN + n)*KK + k0;
    float* pr1 = pe + (((size_t)b*CO + o0+1)*NN + n)*KK + k0;
    #pragma unroll
    for (int q4 = 0; q4 < 3; ++q4) {
        float4 v0, v1;
        v0.x=pev0[q4*4+0]; v0.y=pev0[q4*4+1]; v0.z=pev0[q4*4+2]; v0.w=pev0[q4*4+3];
        v1.x=pev1[q4*4+0]; v1.y=pev1[q4*4+1]; v1.z=pev1[q4*4+2]; v1.w=pev1[q4*4+3];
        ((float4*)pr0)[q4] = v0;
        ((float4*)pr1)[q4] = v1;
    }
}

extern "C" void kernel_launch(void* const* d_in, const int* in_sizes, int n_in,
                              void* d_out, int out_size, void* d_ws, size_t ws_size,
                              hipStream_t stream)
{
    const float* pc  = (const float*)d_in[0];
    const float* f   = (const float*)d_in[1];
    const float* w1  = (const float*)d_in[3];
    const float* g1  = (const float*)d_in[4];
    const float* b1  = (const float*)d_in[5];
    const float* wd1 = (const float*)d_in[6];
    const float* gd1 = (const float*)d_in[7];
    const float* bd1 = (const float*)d_in[8];
    const float* wd2 = (const float*)d_in[9];
    const float* gd2 = (const float*)d_in[10];
    const float* bd2 = (const float*)d_in[11];
    const float* wd3 = (const float*)d_in[12];
    const float* gd3 = (const float*)d_in[13];
    const float* bd3 = (const float*)d_in[14];
    const float* ww  = (const float*)d_in[15];
    const float* gw  = (const float*)d_in[16];
    const float* bw  = (const float*)d_in[17];
    const float* wc2 = (const float*)d_in[18];
    const float* gc2 = (const float*)d_in[19];
    const float* bc2 = (const float*)d_in[20];

    float* out     = (float*)d_out;
    float* outPc   = out;                               // 49152
    float* outFout = out + 49152;                       // 1048576
    float* outPe   = out + 49152 + 1048576;             // 25165824

    char* ws = (char*)d_ws;
    size_t off = 0;
    auto alloc = [&](size_t bytes)->void* {
        void* q = ws + off; off += (bytes + 255) & ~(size_t)255; return q;
    };
    float* p    = (float*)alloc((size_t)GQ*3*4);
    float* pS   = (float*)alloc((size_t)GQ*3*4);
    float* f1T  = (float*)alloc((size_t)BB*NN*CO*4);
    int*   idx  = (int*)  alloc((size_t)BB*NN*KK*4);
    float* dpf  = (float*)alloc((size_t)BB*3*NN*KK*4);
    float* ndp  = (float*)alloc((size_t)BB*3*NN*KK*4);
    float* q2f  = (float*)alloc((size_t)BB*3*NN*KK*4);
    int*   idx2 = (int*)  alloc((size_t)GQ*KK*4);
    float* dp2  = (float*)alloc((size_t)GQ*72*4);
    unsigned short* wwAbf = (unsigned short*)alloc((size_t)CO*CO*2);

    k_f1   <<<dim3(512), dim3(256), 0, stream>>>(f, w1, g1, b1, pc, ww, f1T, outPc, p, pS, wwAbf);
    k_bq1  <<<dim3(GQ/4), dim3(256), 0, stream>>>(pS, idx);
    k_geo  <<<dim3(GQ/8), dim3(256), 0, stream>>>(p, idx, dpf, ndp);
    k_mlp  <<<dim3((BB*NN*KK)/256), dim3(256), 0, stream>>>(ndp, wd1,gd1,bd1, wd2,gd2,bd2, wd3,gd3,bd3, q2f);
    k_bq2  <<<dim3((GQ*KK)/256), dim3(256), 0, stream>>>(dpf, q2f, idx2, dp2);
    k_final<<<dim3(BB*NN/2), dim3(256), 0, stream>>>(f1T, idx, idx2, dp2, wwAbf, gw, bw, wc2, gc2, bc2, outFout, outPe);
}